// Round 8
// baseline (899.365 us; speedup 1.0000x reference)
//
#include <hip/hip_runtime.h>
#include <hip/hip_bf16.h>
#include <cstdint>
#include <cstddef>

// ---------------- problem constants ----------------
#define BB 512
#define SS 500
#define TT 499            // scan steps t = 0..498
#define NRB 256           // recurrence blocks (2 rows each, phase-offset pair)
#define L2E 1.4426950408889634f

typedef float  f32x4  __attribute__((ext_vector_type(4)));
typedef short  bf16x8 __attribute__((ext_vector_type(8)));

#define MFMA16(A, B, C) __builtin_amdgcn_mfma_f32_16x16x32_bf16((A), (B), (C), 0, 0, 0)

// ---------------- workspace layout (bytes) ----------------
static constexpr size_t OFF_TXQ   = 0;                 // 10000*128*4
static constexpr size_t OFF_TXC   = 5120000;           // 500*128*4
static constexpr size_t OFF_TXQD  = 5376000;           // 100*128*4
static constexpr size_t OFF_TXCD  = 5427200;           // 100*128*4
static constexpr size_t OFF_TKIQD = 5478400;           // 100*128*4 (+= Txqd@Wki0)
static constexpr size_t OFF_TKICD = 5529600;           // 100*128*4 (+= Txcd@Wki0)
static constexpr size_t OFF_TKICO = 5580800;           // 2*128*4 (pad 1024)
static constexpr size_t OFF_TP1   = 5581824;           // 2*128*4 (pad 1024), scaled -L2E
static constexpr size_t OFF_TP2   = 5582848;           // 2*128*4 (pad 1024), scaled -2*L2E
static constexpr size_t OFF_TXQ2  = 5583872;           // 10000*128*4 (Txq@Wki0)
static constexpr size_t OFF_TXC2  = 10703872;          // 500*128*4   (Txc@Wki0)
static constexpr size_t OFF_WFRAG = 10959872;          // 5*128*128*2 (pre-scaled bf16)
static constexpr size_t OFF_CPK   = 11123712;          // 256*512 bytes
static constexpr size_t OFF_XCD   = 11254784;          // 504*256*256*4 (1 f32/elem layout)
static constexpr size_t OFF_KIPRE = 143375360;         // 504*256*256*4 (scaled -L2E)
static constexpr size_t OFF_YPART = 275495936;         // 499*256*8*2*4
static constexpr size_t TOTAL_WS  = 283671552;

// fallback scratch if harness workspace is too small
__device__ unsigned char g_fb[TOTAL_WS];

// ---------------- helpers ----------------
__device__ __forceinline__ unsigned short f2bf(float f) {
    union { float f; uint32_t u; } v; v.f = f;
    uint32_t u = v.u;
    uint32_t r = u + 0x7FFFu + ((u >> 16) & 1u);
    return (unsigned short)(r >> 16);
}
__device__ __forceinline__ float fsig(float z) {
    return __builtin_amdgcn_rcpf(1.0f + __expf(-z));
}
// pack 2 f32 -> 2 bf16 (RTNE): dst.lo = cvt(lo), dst.hi = cvt(hi)
__device__ __forceinline__ uint32_t cvtpk(float lo, float hi) {
    uint32_t r;
    asm("v_cvt_pk_bf16_f32 %0, %1, %2" : "=v"(r) : "v"(lo), "v"(hi));
    return r;
}
// barrier that only orders LDS traffic (prefetch loads stay in flight)
__device__ __forceinline__ void bar_lgkm() {
    asm volatile("s_waitcnt lgkmcnt(0)" ::: "memory");
    __builtin_amdgcn_s_barrier();
}
// sum over each 16-lane group via DPP (quad xor1, xor2, half-mirror, mirror)
__device__ __forceinline__ float sum16(float x) {
    int a = __float_as_int(x);
    int b = __builtin_amdgcn_update_dpp(a, a, 0xB1, 0xF, 0xF, false);   // quad xor1
    float s = x + __int_as_float(b);
    int c = __float_as_int(s);
    int d = __builtin_amdgcn_update_dpp(c, c, 0x4E, 0xF, 0xF, false);   // quad xor2
    s += __int_as_float(d);
    int e = __float_as_int(s);
    int f = __builtin_amdgcn_update_dpp(e, e, 0x141, 0xF, 0xF, false);  // row_half_mirror
    s += __int_as_float(f);
    int gg = __float_as_int(s);
    int hh = __builtin_amdgcn_update_dpp(gg, gg, 0x140, 0xF, 0xF, false); // row_mirror
    return s + __int_as_float(hh);
}

// ---------------- P1: per-table GEMM products ----------------
__global__ __launch_bounds__(128) void k_tables(
    const float* __restrict__ Eq, const float* __restrict__ Ec,
    const float* __restrict__ Eqd, const float* __restrict__ Ecd,
    const float* __restrict__ Ecorr,
    const float* __restrict__ Wx,  const float* __restrict__ bx,
    const float* __restrict__ Wpka1, const float* __restrict__ bpka1,
    const float* __restrict__ Wpka2, const float* __restrict__ bpka2,
    const float* __restrict__ Wki, const float* __restrict__ bki,
    float* __restrict__ Txq, float* __restrict__ Txc,
    float* __restrict__ Txqd, float* __restrict__ Txcd,
    float* __restrict__ TkiQd, float* __restrict__ TkiCd, float* __restrict__ TkiCo,
    float* __restrict__ Tp1, float* __restrict__ Tp2)
{
    int blk = blockIdx.x;
    const float* A; const float* W; const float* bias = nullptr; float* out; int row;
    float oscale = 1.0f;
    if      (blk < 10000) { A = Eq;    row = blk;          W = Wx;              bias = bx;    out = Txq;  }
    else if (blk < 10500) { A = Ec;    row = blk - 10000;  W = Wx  + 128*128;                 out = Txc;  }
    else if (blk < 10600) { A = Eqd;   row = blk - 10500;  W = Wx  + 256*128;                 out = Txqd; }
    else if (blk < 10700) { A = Ecd;   row = blk - 10600;  W = Wx  + 384*128;                 out = Txcd; }
    else if (blk < 10800) { A = Eqd;   row = blk - 10700;  W = Wki + 256*128;                 out = TkiQd;}
    else if (blk < 10900) { A = Ecd;   row = blk - 10800;  W = Wki + 384*128;                 out = TkiCd;}
    else if (blk < 10902) { A = Ecorr; row = blk - 10900;  W = Wki + 128*128;   bias = bki;   out = TkiCo;}
    else if (blk < 10904) { A = Ecorr; row = blk - 10902;  W = Wpka1 + 128*128; bias = bpka1; out = Tp1;  oscale = -L2E; }
    else                  { A = Ecorr; row = blk - 10904;  W = Wpka2 + 128*128; bias = bpka2; out = Tp2;  oscale = -2.0f*L2E; }

    __shared__ float a[128];
    int c = threadIdx.x;
    a[c] = A[row * 128 + c];
    __syncthreads();
    float acc = bias ? bias[c] : 0.0f;
    #pragma unroll 8
    for (int k = 0; k < 128; ++k) acc += a[k] * W[k * 128 + c];
    out[row * 128 + c] = acc * oscale;
}

// ---------------- P1b: fold x@Wki0 into tables ----------------
__global__ __launch_bounds__(128) void k_tables2(
    const float* __restrict__ Wki,
    const float* __restrict__ Txq, const float* __restrict__ Txc,
    const float* __restrict__ Txqd, const float* __restrict__ Txcd,
    float* __restrict__ Txq2, float* __restrict__ Txc2,
    float* __restrict__ TkiQd, float* __restrict__ TkiCd)
{
    int blk = blockIdx.x;
    const float* A; float* out; int row; bool accum;
    if      (blk < 10000) { A = Txq;  row = blk;          out = Txq2;  accum = false; }
    else if (blk < 10500) { A = Txc;  row = blk - 10000;  out = Txc2;  accum = false; }
    else if (blk < 10600) { A = Txqd; row = blk - 10500;  out = TkiQd; accum = true;  }
    else                  { A = Txcd; row = blk - 10600;  out = TkiCd; accum = true;  }
    __shared__ float a[128];
    int c = threadIdx.x;
    a[c] = A[row * 128 + c];
    __syncthreads();
    float acc = accum ? out[row * 128 + c] : 0.0f;
    #pragma unroll 8
    for (int k = 0; k < 128; ++k) acc += a[k] * Wki[k * 128 + c];
    out[row * 128 + c] = acc;
}

// ---------------- P0: weight matrices -> MFMA B-fragments (bf16, exp2-prescaled) ----
__global__ __launch_bounds__(64) void k_wfrag(
    const float* __restrict__ Wsdf1, const float* __restrict__ Wsdf2,
    const float* __restrict__ Wpka1, const float* __restrict__ Wpka2,
    const float* __restrict__ Wki, unsigned short* __restrict__ wfrag)
{
    int bid = blockIdx.x;                 // 5 * 8 * 4 = 160
    int m = bid >> 5, w = (bid >> 2) & 7, kt = bid & 3;
    const float* W = (m == 0) ? Wsdf1 : (m == 1) ? Wsdf2 : (m == 2) ? Wpka1 : (m == 3) ? Wpka2 : Wki;
    float sgn = (m == 0) ? -L2E : (m == 1) ? -2.0f*L2E : (m == 2) ? -L2E : (m == 3) ? -2.0f*L2E : L2E;
    int l = threadIdx.x;
    int cc = w * 16 + (l & 15);
    int k0 = kt * 32 + ((l >> 4) << 3);
    unsigned short v[8];
    #pragma unroll
    for (int j = 0; j < 8; ++j) v[j] = f2bf(sgn * W[(size_t)(k0 + j) * 128 + cc]);
    unsigned short* dst = wfrag + ((( (size_t)m * 8 + w) * 4 + kt) * 64 + l) * 8;
    #pragma unroll
    for (int j = 0; j < 8; ++j) dst[j] = v[j];
}

// ---------------- P2: materialize x / kipre, 256 f32 per (t, rb) ----------------
__global__ __launch_bounds__(256) void k_gather(
    const int* __restrict__ qs, const int* __restrict__ cs,
    const int* __restrict__ qds, const int* __restrict__ cds, const int* __restrict__ corr,
    const float* __restrict__ Txq, const float* __restrict__ Txc,
    const float* __restrict__ Txqd, const float* __restrict__ Txcd,
    const float* __restrict__ Txq2, const float* __restrict__ Txc2,
    const float* __restrict__ TkiQd, const float* __restrict__ TkiCd, const float* __restrict__ TkiCo,
    float* __restrict__ xcd, float* __restrict__ kipre, unsigned char* __restrict__ cpk)
{
    int bid = blockIdx.x;            // bid = t*256 + rb
    int t = bid >> 8, rb = bid & 255;
    int tid = threadIdx.x;
    int row = tid >> 7;
    int col = tid & 127;
    int b = rb * 2 + row;

    int iq  = qs  [(size_t)b * SS + t];
    int ic  = cs  [(size_t)b * SS + t];
    int iqd = qds [(size_t)b * SS + t];
    int icd = cds [(size_t)b * SS + t];
    int ico = corr[(size_t)b * SS + t];

    float x = Txq [(size_t)iq  * 128 + col] + Txc [(size_t)ic  * 128 + col]
            + Txqd[(size_t)iqd * 128 + col] + Txcd[(size_t)icd * 128 + col];
    float k = (Txq2 [(size_t)iq  * 128 + col] + Txc2 [(size_t)ic  * 128 + col]
             + TkiQd[(size_t)iqd * 128 + col] + TkiCd[(size_t)icd * 128 + col]
             + TkiCo[(size_t)ico * 128 + col]) * (-L2E);

    xcd  [(size_t)bid * 256 + tid] = x;
    kipre[(size_t)bid * 256 + tid] = k;

    if (tid == 0) {
        unsigned char bpk = 0;
        #pragma unroll
        for (int r = 0; r < 2; ++r)
            bpk |= (unsigned char)((corr[(size_t)(rb * 2 + r) * SS + t] & 1) << r);
        cpk[(size_t)rb * 512 + t] = bpk;
    }
}

// ---------------- recurrence: 256 blocks x 512 threads, 2 phase-offset row streams ----
// Each block owns rows {rb*2 (A), rb*2+1 (B)}, processed as two M=1 streams offset by
// one barrier interval:  int1 = PH1(A,t) || PH2(B,t);  int2 = PH2(A,t) || PH1(B,t+1).
// Dup-16 A-tile: LDS holds one 128-col row per buffer (256B); fragment reads at
// byte (kt*64 + g*16), lane-uniform in cl -> broadcast, conflict-free. All 16 C rows
// duplicate row 0 -> result is acc[0] for every lane, no selects.
// Buffers alternate write-interval/read-interval with a barrier between (race-free).
__global__ __launch_bounds__(512, 2) void k_rec(
    const float* __restrict__ xcd, const float* __restrict__ kipre,
    const unsigned char* __restrict__ cpkg,
    const unsigned short* __restrict__ wfrag,
    const float* __restrict__ Tp1, const float* __restrict__ Tp2,
    const float* __restrict__ bsdf1, const float* __restrict__ bsdf2,
    const float* __restrict__ h0, float* __restrict__ ypart)
{
    int rb = blockIdx.x;
    int tid = threadIdx.x;
    int w = tid >> 6, l = tid & 63;
    int g = l >> 4, cl = l & 15;
    int col = w * 16 + cl;
    bool owner = (g == 0);           // lanes that perform LDS writes
    bool ystore = (l == 0);

    __shared__ __align__(16) unsigned short dbufA[128];
    __shared__ __align__(16) unsigned short sbufA[128];
    __shared__ __align__(16) unsigned short dbufB[128];
    __shared__ __align__(16) unsigned short sbufB[128];

    // weight B-fragments (5 matrices x 4 k-tiles), exp2-prescaled
    bf16x8 wf[5][4];
    #pragma unroll
    for (int m = 0; m < 5; ++m)
        #pragma unroll
        for (int kt = 0; kt < 4; ++kt)
            wf[m][kt] = *(const bf16x8*)(wfrag + ((((size_t)m * 8 + w) * 4 + kt) * 64 + l) * 8);

    float bs1 = bsdf1[col] * (-L2E);
    float bs2 = bsdf2[col] * (-2.0f * L2E);
    float tp1a = Tp1[col], tp1b = Tp1[128 + col];   // pre-scaled -L2E
    float tp2a = Tp2[col], tp2b = Tp2[128 + col];   // pre-scaled -2L2E

    float hA = h0[(size_t)(rb * 2 + 0) * 128 + col];
    float hB = h0[(size_t)(rb * 2 + 1) * 128 + col];

    // LDS pointers
    char* pdwA = (char*)dbufA + col * 2;
    char* pswA = (char*)sbufA + col * 2;
    char* pdwB = (char*)dbufB + col * 2;
    char* pswB = (char*)sbufB + col * 2;
    const char* rdA = (const char*)dbufA + g * 16;
    const char* rsA = (const char*)sbufA + g * 16;
    const char* rdB = (const char*)dbufB + g * 16;
    const char* rsB = (const char*)sbufB + g * 16;

    const size_t TSTR = (size_t)NRB * 256;   // per-t stride in f32 elements
    const float* xpA = xcd + (size_t)rb * 256 + col;
    const float* xpB = xpA + 128;
    const float* kpA = kipre + (size_t)rb * 256 + col;
    const float* kpB = kpA + 128;
    const unsigned char* cp = cpkg + (size_t)rb * 512;

    // initial stream state
    float xA0 = xpA[0], xB0 = xpB[0];
    float kipA0 = kpA[0];                 // kip_A(t) for PH1(A,t), t=0
    float kipB0 = kpB[0];
    float xA1 = xpA[TSTR], xB1 = xpB[TSTR];
    float kipB1 = kpB[TSTR];              // kip_B(t+1) for PH1(B,t+1), t=0
    unsigned char cpk0 = cp[0];
    unsigned int cA0 = cpk0 & 1u, cB0 = (cpk0 >> 1) & 1u;

    // y-partial pointers: ypart[t][rb][w][pair]
    float* yptA = ypart + ((size_t)rb * 8 + w) * 2;
    float* yptB = yptA + 1;
    const size_t YSTR = (size_t)NRB * 16;   // 4096 floats per t

    // ---- prologue: d_A(0), d_B(0) -> LDS; then PH1(B,0) so B enters loop half-ahead
    if (owner) {
        *(unsigned short*)pdwA = (unsigned short)cvtpk(xA0 - hA, xA0 - hA);
        *(unsigned short*)pdwB = (unsigned short)cvtpk(xB0 - hB, xB0 - hB);
    }
    bar_lgkm();
    float gvA, gvB;
    {
        bf16x8 b0 = *(const bf16x8*)(rdB +   0);
        bf16x8 b1 = *(const bf16x8*)(rdB +  64);
        bf16x8 b2 = *(const bf16x8*)(rdB + 128);
        bf16x8 b3 = *(const bf16x8*)(rdB + 192);
        f32x4 s1a = {bs1,bs1,bs1,bs1}, s1b = {0.f,0.f,0.f,0.f};
        f32x4 s2a = {bs2,bs2,bs2,bs2}, s2b = {0.f,0.f,0.f,0.f};
        f32x4 gda = {0.f,0.f,0.f,0.f}, gdb = {0.f,0.f,0.f,0.f};
        s1a = MFMA16(b0, wf[0][0], s1a); s2a = MFMA16(b0, wf[1][0], s2a); gda = MFMA16(b0, wf[4][0], gda);
        s1b = MFMA16(b2, wf[0][2], s1b); s2b = MFMA16(b2, wf[1][2], s2b); gdb = MFMA16(b2, wf[4][2], gdb);
        s1a = MFMA16(b1, wf[0][1], s1a); s2a = MFMA16(b1, wf[1][1], s2a); gda = MFMA16(b1, wf[4][1], gda);
        s1b = MFMA16(b3, wf[0][3], s1b); s2b = MFMA16(b3, wf[1][3], s2b); gdb = MFMA16(b3, wf[4][3], gdb);
        float s1v = s1a[0] + s1b[0], s2v = s2a[0] + s2b[0], gdv = gda[0] + gdb[0];
        gvB = __builtin_amdgcn_rcpf(1.0f + __builtin_amdgcn_exp2f(gdv + kipB0));
        float e1 = __builtin_amdgcn_exp2f(s1v), e2 = __builtin_amdgcn_exp2f(s2v);
        float sdf = (1.0f - e2) * __builtin_amdgcn_rcpf((1.0f + e1) * (1.0f + e2));
        if (owner) *(unsigned short*)pswB = (unsigned short)cvtpk(sdf, sdf);
    }
    bar_lgkm();

    #pragma unroll 1
    for (int t = 0; t < TT; ++t) {
        // ---- prefetch for next iteration (not waited before barriers) ----
        float xA1n   = xpA[(size_t)(t + 2) * TSTR];
        float xB1n   = xpB[(size_t)(t + 2) * TSTR];
        float kipA0n = kpA[(size_t)(t + 1) * TSTR];
        float kipB1n = kpB[(size_t)(t + 2) * TSTR];
        unsigned char cpkN = cp[t + 1];

        // ======== interval 1: PH1(A,t) || PH2(B,t) ========
        {
            bf16x8 a0 = *(const bf16x8*)(rdA +   0);
            bf16x8 a1 = *(const bf16x8*)(rdA +  64);
            bf16x8 a2 = *(const bf16x8*)(rdA + 128);
            bf16x8 a3 = *(const bf16x8*)(rdA + 192);
            bf16x8 f0 = *(const bf16x8*)(rsB +   0);
            bf16x8 f1 = *(const bf16x8*)(rsB +  64);
            bf16x8 f2 = *(const bf16x8*)(rsB + 128);
            bf16x8 f3 = *(const bf16x8*)(rsB + 192);
            f32x4 s1a = {bs1,bs1,bs1,bs1}, s1b = {0.f,0.f,0.f,0.f};
            f32x4 s2a = {bs2,bs2,bs2,bs2}, s2b = {0.f,0.f,0.f,0.f};
            f32x4 gda = {0.f,0.f,0.f,0.f}, gdb = {0.f,0.f,0.f,0.f};
            f32x4 p1a = {0.f,0.f,0.f,0.f}, p1b = {0.f,0.f,0.f,0.f};
            f32x4 p2a = {0.f,0.f,0.f,0.f}, p2b = {0.f,0.f,0.f,0.f};
            s1a = MFMA16(a0, wf[0][0], s1a); p1a = MFMA16(f0, wf[2][0], p1a);
            s2a = MFMA16(a0, wf[1][0], s2a); p2a = MFMA16(f0, wf[3][0], p2a);
            gda = MFMA16(a0, wf[4][0], gda);
            s1b = MFMA16(a2, wf[0][2], s1b); p1b = MFMA16(f2, wf[2][2], p1b);
            s2b = MFMA16(a2, wf[1][2], s2b); p2b = MFMA16(f2, wf[3][2], p2b);
            gdb = MFMA16(a2, wf[4][2], gdb);
            s1a = MFMA16(a1, wf[0][1], s1a); p1a = MFMA16(f1, wf[2][1], p1a);
            s2a = MFMA16(a1, wf[1][1], s2a); p2a = MFMA16(f1, wf[3][1], p2a);
            gda = MFMA16(a1, wf[4][1], gda);
            s1b = MFMA16(a3, wf[0][3], s1b); p1b = MFMA16(f3, wf[2][3], p1b);
            s2b = MFMA16(a3, wf[1][3], s2b); p2b = MFMA16(f3, wf[3][3], p2b);
            gdb = MFMA16(a3, wf[4][3], gdb);
            // A post (phase 1): gvA + sdf_A -> sbufA
            float s1v = s1a[0] + s1b[0], s2v = s2a[0] + s2b[0], gdv = gda[0] + gdb[0];
            gvA = __builtin_amdgcn_rcpf(1.0f + __builtin_amdgcn_exp2f(gdv + kipA0));
            float e1 = __builtin_amdgcn_exp2f(s1v), e2 = __builtin_amdgcn_exp2f(s2v);
            float sdf = (1.0f - e2) * __builtin_amdgcn_rcpf((1.0f + e1) * (1.0f + e2));
            if (owner) *(unsigned short*)pswA = (unsigned short)cvtpk(sdf, sdf);
            // B post (phase 2): h_B update, d_B(t+1) -> dbufB, y_B
            float p1v = p1a[0] + p1b[0], p2v = p2a[0] + p2b[0];
            float t1 = cB0 ? tp1b : tp1a;
            float t2 = cB0 ? tp2b : tp2a;
            float e1p = __builtin_amdgcn_exp2f(p1v + t1), e2p = __builtin_amdgcn_exp2f(p2v + t2);
            float pka = (1.0f - e2p) * __builtin_amdgcn_rcpf((1.0f + e1p) * (1.0f + e2p));
            hB = gvB * (hB - pka) + pka;
            if (owner) *(unsigned short*)pdwB = (unsigned short)cvtpk(xB1 - hB, xB1 - hB);
            float yB = sum16(xB1 * hB);
            if (ystore) yptB[0] = yB;
        }
        bar_lgkm();

        // ======== interval 2: PH2(A,t) || PH1(B,t+1) ========
        {
            bf16x8 a0 = *(const bf16x8*)(rsA +   0);
            bf16x8 a1 = *(const bf16x8*)(rsA +  64);
            bf16x8 a2 = *(const bf16x8*)(rsA + 128);
            bf16x8 a3 = *(const bf16x8*)(rsA + 192);
            bf16x8 f0 = *(const bf16x8*)(rdB +   0);
            bf16x8 f1 = *(const bf16x8*)(rdB +  64);
            bf16x8 f2 = *(const bf16x8*)(rdB + 128);
            bf16x8 f3 = *(const bf16x8*)(rdB + 192);
            f32x4 p1a = {0.f,0.f,0.f,0.f}, p1b = {0.f,0.f,0.f,0.f};
            f32x4 p2a = {0.f,0.f,0.f,0.f}, p2b = {0.f,0.f,0.f,0.f};
            f32x4 s1a = {bs1,bs1,bs1,bs1}, s1b = {0.f,0.f,0.f,0.f};
            f32x4 s2a = {bs2,bs2,bs2,bs2}, s2b = {0.f,0.f,0.f,0.f};
            f32x4 gda = {0.f,0.f,0.f,0.f}, gdb = {0.f,0.f,0.f,0.f};
            p1a = MFMA16(a0, wf[2][0], p1a); s1a = MFMA16(f0, wf[0][0], s1a);
            p2a = MFMA16(a0, wf[3][0], p2a); s2a = MFMA16(f0, wf[1][0], s2a);
            gda = MFMA16(f0, wf[4][0], gda);
            p1b = MFMA16(a2, wf[2][2], p1b); s1b = MFMA16(f2, wf[0][2], s1b);
            p2b = MFMA16(a2, wf[3][2], p2b); s2b = MFMA16(f2, wf[1][2], s2b);
            gdb = MFMA16(f2, wf[4][2], gdb);
            p1a = MFMA16(a1, wf[2][1], p1a); s1a = MFMA16(f1, wf[0][1], s1a);
            p2a = MFMA16(a1, wf[3][1], p2a); s2a = MFMA16(f1, wf[1][1], s2a);
            gda = MFMA16(f1, wf[4][1], gda);
            p1b = MFMA16(a3, wf[2][3], p1b); s1b = MFMA16(f3, wf[0][3], s1b);
            p2b = MFMA16(a3, wf[3][3], p2b); s2b = MFMA16(f3, wf[1][3], s2b);
            gdb = MFMA16(f3, wf[4][3], gdb);
            // A post (phase 2): h_A update, d_A(t+1) -> dbufA, y_A
            float p1v = p1a[0] + p1b[0], p2v = p2a[0] + p2b[0];
            float t1 = cA0 ? tp1b : tp1a;
            float t2 = cA0 ? tp2b : tp2a;
            float e1p = __builtin_amdgcn_exp2f(p1v + t1), e2p = __builtin_amdgcn_exp2f(p2v + t2);
            float pka = (1.0f - e2p) * __builtin_amdgcn_rcpf((1.0f + e1p) * (1.0f + e2p));
            hA = gvA * (hA - pka) + pka;
            if (owner) *(unsigned short*)pdwA = (unsigned short)cvtpk(xA1 - hA, xA1 - hA);
            float yA = sum16(xA1 * hA);
            if (ystore) yptA[0] = yA;
            // B post (phase 1, step t+1): gvB + sdf_B(t+1) -> sbufB
            float s1v = s1a[0] + s1b[0], s2v = s2a[0] + s2b[0], gdv = gda[0] + gdb[0];
            gvB = __builtin_amdgcn_rcpf(1.0f + __builtin_amdgcn_exp2f(gdv + kipB1));
            float e1 = __builtin_amdgcn_exp2f(s1v), e2 = __builtin_amdgcn_exp2f(s2v);
            float sdf = (1.0f - e2) * __builtin_amdgcn_rcpf((1.0f + e1) * (1.0f + e2));
            if (owner) *(unsigned short*)pswB = (unsigned short)cvtpk(sdf, sdf);
        }
        bar_lgkm();

        // rotate stream registers
        yptA += YSTR; yptB += YSTR;
        xA1 = xA1n; xB1 = xB1n; kipA0 = kipA0n; kipB1 = kipB1n;
        cA0 = cpkN & 1u; cB0 = (cpkN >> 1) & 1u;
    }
}

// ---------------- final: y[b][t] = sigmoid(sum of 8 wave partials); y[:,499] = 0 ------
__global__ __launch_bounds__(256) void k_yfinal(const float* __restrict__ ypart, float* __restrict__ y)
{
    int id = blockIdx.x * 256 + threadIdx.x;
    if (id >= BB * SS) return;
    int b = id / SS, t = id - b * SS;
    if (t == TT) { y[id] = 0.0f; return; }
    int rb = b >> 1, pair = b & 1;
    const float* base = ypart + (size_t)t * NRB * 16 + (size_t)rb * 16 + pair;
    float s = 0.0f;
    #pragma unroll
    for (int w = 0; w < 8; ++w) s += base[w * 2];
    y[id] = fsig(s);
}

// ---------------- launch ----------------
extern "C" void kernel_launch(void* const* d_in, const int* in_sizes, int n_in,
                              void* d_out, int out_size, void* d_ws, size_t ws_size,
                              hipStream_t stream) {
    const int* qs    = (const int*)d_in[0];
    const int* cs    = (const int*)d_in[1];
    const int* qds   = (const int*)d_in[2];
    const int* cds   = (const int*)d_in[3];
    const int* corr  = (const int*)d_in[4];
    const float* Eq    = (const float*)d_in[5];
    const float* Ec    = (const float*)d_in[6];
    const float* Eqd   = (const float*)d_in[7];
    const float* Ecd   = (const float*)d_in[8];
    const float* Ecorr = (const float*)d_in[9];
    const float* Wx    = (const float*)d_in[10];
    const float* bx    = (const float*)d_in[11];
    const float* Wsdf1 = (const float*)d_in[12];
    const float* bsdf1 = (const float*)d_in[13];
    const float* Wsdf2 = (const float*)d_in[14];
    const float* bsdf2 = (const float*)d_in[15];
    const float* Wpka1 = (const float*)d_in[16];
    const float* bpka1 = (const float*)d_in[17];
    const float* Wpka2 = (const float*)d_in[18];
    const float* bpka2 = (const float*)d_in[19];
    const float* Wki   = (const float*)d_in[20];
    const float* bki   = (const float*)d_in[21];
    const float* h0    = (const float*)d_in[22];

    char* base;
    if (ws_size >= TOTAL_WS) {
        base = (char*)d_ws;
    } else {
        void* p = nullptr;
        hipGetSymbolAddress(&p, HIP_SYMBOL(g_fb));
        base = (char*)p;
    }

    float* Txq   = (float*)(base + OFF_TXQ);
    float* Txc   = (float*)(base + OFF_TXC);
    float* Txqd  = (float*)(base + OFF_TXQD);
    float* Txcd  = (float*)(base + OFF_TXCD);
    float* TkiQd = (float*)(base + OFF_TKIQD);
    float* TkiCd = (float*)(base + OFF_TKICD);
    float* TkiCo = (float*)(base + OFF_TKICO);
    float* Tp1   = (float*)(base + OFF_TP1);
    float* Tp2   = (float*)(base + OFF_TP2);
    float* Txq2  = (float*)(base + OFF_TXQ2);
    float* Txc2  = (float*)(base + OFF_TXC2);
    unsigned short* wfrag = (unsigned short*)(base + OFF_WFRAG);
    unsigned char*  cpk   = (unsigned char*)(base + OFF_CPK);
    float* xcd   = (float*)(base + OFF_XCD);
    float* kipre = (float*)(base + OFF_KIPRE);
    float* ypart = (float*)(base + OFF_YPART);

    k_tables<<<10906, 128, 0, stream>>>(Eq, Ec, Eqd, Ecd, Ecorr, Wx, bx,
                                        Wpka1, bpka1, Wpka2, bpka2, Wki, bki,
                                        Txq, Txc, Txqd, Txcd, TkiQd, TkiCd, TkiCo, Tp1, Tp2);
    k_tables2<<<10700, 128, 0, stream>>>(Wki, Txq, Txc, Txqd, Txcd, Txq2, Txc2, TkiQd, TkiCd);
    k_wfrag<<<160, 64, 0, stream>>>(Wsdf1, Wsdf2, Wpka1, Wpka2, Wki, wfrag);
    k_gather<<<SS * NRB, 256, 0, stream>>>(qs, cs, qds, cds, corr,
                                           Txq, Txc, Txqd, Txcd, Txq2, Txc2,
                                           TkiQd, TkiCd, TkiCo, xcd, kipre, cpk);
    k_rec<<<NRB, 512, 0, stream>>>(xcd, kipre, cpk, wfrag, Tp1, Tp2,
                                   bsdf1, bsdf2, h0, ypart);
    k_yfinal<<<(BB * SS + 255) / 256, 256, 0, stream>>>(ypart, (float*)d_out);
}

// Round 9
// 530.946 us; speedup vs baseline: 1.6939x; 1.6939x over previous
//
#include <hip/hip_runtime.h>
#include <hip/hip_bf16.h>
#include <cstdint>
#include <cstddef>

// ---------------- problem constants ----------------
#define BB 512
#define SS 500
#define TT 499            // scan steps t = 0..498
#define NRB 256           // recurrence blocks (2 rows each)
#define L2E 1.4426950408889634f

typedef float  f32x4  __attribute__((ext_vector_type(4)));
typedef short  bf16x8 __attribute__((ext_vector_type(8)));

#define MFMA16(A, B, C) __builtin_amdgcn_mfma_f32_16x16x32_bf16((A), (B), (C), 0, 0, 0)

// ---------------- workspace layout (bytes) ----------------
// interleaved tables: element [row*128+col] = float2 { x-part, kip-part(-L2E-scaled) }
static constexpr size_t OFF_TQ    = 0;                 // 10000*128*8
static constexpr size_t OFF_TC    = 10240000;          // 500*128*8
static constexpr size_t OFF_TQD   = 10752000;          // 100*128*8
static constexpr size_t OFF_TCD   = 10854400;          // 100*128*8
static constexpr size_t OFF_TCOK  = 10956800;          // 2*128*4 (kip co part, -L2E)
static constexpr size_t OFF_TP1   = 10957824;          // 2*128*4, scaled -L2E
static constexpr size_t OFF_TP2   = 10958848;          // 2*128*4, scaled -2*L2E
static constexpr size_t OFF_TMPA  = 10959872;          // 100*128*4 raw Eqd@Wki2
static constexpr size_t OFF_TMPB  = 11011072;          // 100*128*4 raw Ecd@Wki3
static constexpr size_t OFF_WFRAG = 11062272;          // 5*128*128*2 (pre-scaled bf16)
static constexpr size_t OFF_YPART = 11226112;          // 499*256*16*4
static constexpr size_t TOTAL_WS  = 19401728;

// fallback scratch if harness workspace is too small
__device__ unsigned char g_fb[TOTAL_WS];

// ---------------- helpers ----------------
__device__ __forceinline__ unsigned short f2bf(float f) {
    union { float f; uint32_t u; } v; v.f = f;
    uint32_t u = v.u;
    uint32_t r = u + 0x7FFFu + ((u >> 16) & 1u);
    return (unsigned short)(r >> 16);
}
__device__ __forceinline__ float fsig(float z) {
    return __builtin_amdgcn_rcpf(1.0f + __expf(-z));
}
// pack 2 f32 -> 2 bf16 (RTNE): dst.lo = cvt(lo), dst.hi = cvt(hi)
__device__ __forceinline__ uint32_t cvtpk(float lo, float hi) {
    uint32_t r;
    asm("v_cvt_pk_bf16_f32 %0, %1, %2" : "=v"(r) : "v"(lo), "v"(hi));
    return r;
}
// barrier that only orders LDS traffic (prefetch loads stay in flight)
__device__ __forceinline__ void bar_lgkm() {
    asm volatile("s_waitcnt lgkmcnt(0)" ::: "memory");
    __builtin_amdgcn_s_barrier();
}
// sum over each 16-lane group via DPP (quad xor1, xor2, half-mirror, mirror)
__device__ __forceinline__ float sum16(float x) {
    int a = __float_as_int(x);
    int b = __builtin_amdgcn_update_dpp(a, a, 0xB1, 0xF, 0xF, false);   // quad xor1
    float s = x + __int_as_float(b);
    int c = __float_as_int(s);
    int d = __builtin_amdgcn_update_dpp(c, c, 0x4E, 0xF, 0xF, false);   // quad xor2
    s += __int_as_float(d);
    int e = __float_as_int(s);
    int f = __builtin_amdgcn_update_dpp(e, e, 0x141, 0xF, 0xF, false);  // row_half_mirror
    s += __int_as_float(f);
    int gg = __float_as_int(s);
    int hh = __builtin_amdgcn_update_dpp(gg, gg, 0x140, 0xF, 0xF, false); // row_mirror
    return s + __int_as_float(hh);
}

// ---------------- P1: per-table GEMM products (x-parts + raw ki tmps) ----------------
__global__ __launch_bounds__(128) void k_tables(
    const float* __restrict__ Eq, const float* __restrict__ Ec,
    const float* __restrict__ Eqd, const float* __restrict__ Ecd,
    const float* __restrict__ Ecorr,
    const float* __restrict__ Wx,  const float* __restrict__ bx,
    const float* __restrict__ Wpka1, const float* __restrict__ bpka1,
    const float* __restrict__ Wpka2, const float* __restrict__ bpka2,
    const float* __restrict__ Wki, const float* __restrict__ bki,
    float* __restrict__ TQ, float* __restrict__ TC,
    float* __restrict__ TQD, float* __restrict__ TCD,
    float* __restrict__ TCOk, float* __restrict__ Tp1, float* __restrict__ Tp2,
    float* __restrict__ tmpA, float* __restrict__ tmpB)
{
    int blk = blockIdx.x;
    const float* A; const float* W; const float* bias = nullptr; float* out; int row;
    int ostride = 1;
    float oscale = 1.0f;
    if      (blk < 10000) { A = Eq;    row = blk;          W = Wx;              bias = bx;    out = TQ;   ostride = 2; }
    else if (blk < 10500) { A = Ec;    row = blk - 10000;  W = Wx  + 128*128;                 out = TC;   ostride = 2; }
    else if (blk < 10600) { A = Eqd;   row = blk - 10500;  W = Wx  + 256*128;                 out = TQD;  ostride = 2; }
    else if (blk < 10700) { A = Ecd;   row = blk - 10600;  W = Wx  + 384*128;                 out = TCD;  ostride = 2; }
    else if (blk < 10800) { A = Eqd;   row = blk - 10700;  W = Wki + 256*128;                 out = tmpA; }
    else if (blk < 10900) { A = Ecd;   row = blk - 10800;  W = Wki + 384*128;                 out = tmpB; }
    else if (blk < 10902) { A = Ecorr; row = blk - 10900;  W = Wki + 128*128;   bias = bki;   out = TCOk; oscale = -L2E; }
    else if (blk < 10904) { A = Ecorr; row = blk - 10902;  W = Wpka1 + 128*128; bias = bpka1; out = Tp1;  oscale = -L2E; }
    else                  { A = Ecorr; row = blk - 10904;  W = Wpka2 + 128*128; bias = bpka2; out = Tp2;  oscale = -2.0f*L2E; }

    __shared__ float a[128];
    int c = threadIdx.x;
    a[c] = A[row * 128 + c];
    __syncthreads();
    float acc = bias ? bias[c] : 0.0f;
    #pragma unroll 8
    for (int k = 0; k < 128; ++k) acc += a[k] * W[k * 128 + c];
    out[(size_t)(row * 128 + c) * ostride] = acc * oscale;
}

// ---------------- P1b: kip-parts (.y) = (x-part @ Wki0 [+ raw tmp]) * -L2E ----------
__global__ __launch_bounds__(128) void k_tables2(
    const float* __restrict__ Wki,
    float* __restrict__ TQ, float* __restrict__ TC,
    float* __restrict__ TQD, float* __restrict__ TCD,
    const float* __restrict__ tmpA, const float* __restrict__ tmpB)
{
    int blk = blockIdx.x;
    float* base2; const float* tmp = nullptr; int row;
    if      (blk < 10000) { row = blk;          base2 = TQ  + (size_t)row * 256; }
    else if (blk < 10500) { row = blk - 10000;  base2 = TC  + (size_t)row * 256; }
    else if (blk < 10600) { row = blk - 10500;  base2 = TQD + (size_t)row * 256; tmp = tmpA + (size_t)row * 128; }
    else                  { row = blk - 10600;  base2 = TCD + (size_t)row * 256; tmp = tmpB + (size_t)row * 128; }
    __shared__ float a[128];
    int c = threadIdx.x;
    a[c] = base2[c * 2];          // x-part
    __syncthreads();
    float acc = tmp ? tmp[c] : 0.0f;
    #pragma unroll 8
    for (int k = 0; k < 128; ++k) acc += a[k] * Wki[k * 128 + c];
    base2[c * 2 + 1] = acc * (-L2E);
}

// ---------------- P0: weight matrices -> MFMA B-fragments (bf16, exp2-prescaled) ----
__global__ __launch_bounds__(64) void k_wfrag(
    const float* __restrict__ Wsdf1, const float* __restrict__ Wsdf2,
    const float* __restrict__ Wpka1, const float* __restrict__ Wpka2,
    const float* __restrict__ Wki, unsigned short* __restrict__ wfrag)
{
    int bid = blockIdx.x;                 // 5 * 8 * 4 = 160
    int m = bid >> 5, w = (bid >> 2) & 7, kt = bid & 3;
    const float* W = (m == 0) ? Wsdf1 : (m == 1) ? Wsdf2 : (m == 2) ? Wpka1 : (m == 3) ? Wpka2 : Wki;
    float sgn = (m == 0) ? -L2E : (m == 1) ? -2.0f*L2E : (m == 2) ? -L2E : (m == 3) ? -2.0f*L2E : L2E;
    int l = threadIdx.x;
    int cc = w * 16 + (l & 15);
    int k0 = kt * 32 + ((l >> 4) << 3);
    unsigned short v[8];
    #pragma unroll
    for (int j = 0; j < 8; ++j) v[j] = f2bf(sgn * W[(size_t)(k0 + j) * 128 + cc]);
    unsigned short* dst = wfrag + ((( (size_t)m * 8 + w) * 4 + kt) * 64 + l) * 8;
    #pragma unroll
    for (int j = 0; j < 8; ++j) dst[j] = v[j];
}

// ---------------- recurrence: 256 blocks x 512 threads (8 waves, 2 rows/block) --------
// R7-verified core (dup-8 A-tile, 2-chain MFMA split, swizzled 2-row LDS) + INLINE
// gather: per step each lane loads 5 seq indices + 4 interleaved float2 table rows
// + 1 f32 (co kip part) for t+2, replacing the materialized xcd/kipre streams.
__global__ __launch_bounds__(512, 2) void k_rec(
    const int* __restrict__ qs, const int* __restrict__ cs,
    const int* __restrict__ qds, const int* __restrict__ cds, const int* __restrict__ corr,
    const float2* __restrict__ TQ, const float2* __restrict__ TC,
    const float2* __restrict__ TQD, const float2* __restrict__ TCD,
    const float* __restrict__ TCOk,
    const unsigned short* __restrict__ wfrag,
    const float* __restrict__ Tp1, const float* __restrict__ Tp2,
    const float* __restrict__ bsdf1, const float* __restrict__ bsdf2,
    const float* __restrict__ h0, float* __restrict__ ypart)
{
    int rb = blockIdx.x;
    int tid = threadIdx.x;
    int w = tid >> 6, l = tid & 63;
    int g = l >> 4, cl = l & 15;
    int col = w * 16 + cl;
    int row = g & 1;                 // owned logical row
    bool owner = (g < 2);            // non-dup lanes (do LDS writes / y stores)

    __shared__ __align__(16) unsigned short dbuf[256];   // 2 rows x 128 cols bf16
    __shared__ __align__(16) unsigned short sbuf[256];

    // weight B-fragments (5 matrices x 4 k-tiles), exp2-prescaled
    bf16x8 wf[5][4];
    #pragma unroll
    for (int m = 0; m < 5; ++m)
        #pragma unroll
        for (int kt = 0; kt < 4; ++kt)
            wf[m][kt] = *(const bf16x8*)(wfrag + ((((size_t)m * 8 + w) * 4 + kt) * 64 + l) * 8);

    float bs1 = bsdf1[col] * (-L2E);
    float bs2 = bsdf2[col] * (-2.0f * L2E);
    float tp1a = Tp1[col], tp1b = Tp1[128 + col];   // pre-scaled -L2E
    float tp2a = Tp2[col], tp2b = Tp2[128 + col];   // pre-scaled -2L2E

    float h = h0[(size_t)(rb * 2 + row) * 128 + col];

    // LDS byte addresses (swizzled; verified conflict-free reads in R7)
    char* pdw = (char*)dbuf + row * 256 + ((col * 2) ^ (row << 6));
    char* psw = (char*)sbuf + row * 256 + ((col * 2) ^ (row << 6));
    const bf16x8* prd[4]; const bf16x8* prs[4];
    int rrow = cl & 1;
    #pragma unroll
    for (int kt = 0; kt < 4; ++kt) {
        int off = rrow * 256 + ((kt * 64 + g * 16) ^ (rrow << 6));
        prd[kt] = (const bf16x8*)((char*)dbuf + off);
        prs[kt] = (const bf16x8*)((char*)sbuf + off);
    }

    // ---- inline gather setup ----
    int boff = (rb * 2 + row) * SS;   // sequence base for this lane's row

    // y-partial pointer: ypart[t][rb][w*2 + row]
    float* ypt = ypart + (size_t)rb * 16 + w * 2 + row;
    const size_t YSTR = (size_t)NRB * 16;
    bool ystore = (owner && cl == 0);

    // prologue: gather t=0 and t=1; write d0
    float x1, kip0, kip1; unsigned int c0, c1;
    {
        int o0 = boff;
        int iq = qs[o0], ic = cs[o0], iqd = qds[o0], icd = cds[o0], ico = corr[o0];
        float2 q = TQ[(size_t)iq * 128 + col], c_ = TC[(size_t)ic * 128 + col];
        float2 qd = TQD[(size_t)iqd * 128 + col], cd = TCD[(size_t)icd * 128 + col];
        float co = TCOk[(size_t)ico * 128 + col];
        float x0 = q.x + c_.x + qd.x + cd.x;
        kip0 = q.y + c_.y + qd.y + cd.y + co;
        c0 = (unsigned int)ico & 1u;
        uint32_t pk = cvtpk(x0 - h, x0 - h);
        if (owner) *(unsigned short*)pdw = (unsigned short)pk;
    }
    {
        int o1 = boff + 1;
        int iq = qs[o1], ic = cs[o1], iqd = qds[o1], icd = cds[o1], ico = corr[o1];
        float2 q = TQ[(size_t)iq * 128 + col], c_ = TC[(size_t)ic * 128 + col];
        float2 qd = TQD[(size_t)iqd * 128 + col], cd = TCD[(size_t)icd * 128 + col];
        float co = TCOk[(size_t)ico * 128 + col];
        x1 = q.x + c_.x + qd.x + cd.x;
        kip1 = q.y + c_.y + qd.y + cd.y + co;
        c1 = (unsigned int)ico & 1u;
    }
    bar_lgkm();

    #pragma unroll 2
    for (int t = 0; t < TT; ++t) {
        // ---- inline gather for t+2 (consumed next iteration; latency hidden) ----
        int tp = t + 2; tp = (tp > 499) ? 499 : tp;
        int op = boff + tp;
        int iq = qs[op], ic = cs[op], iqd = qds[op], icd = cds[op], ico = corr[op];
        float2 gq = TQ[(size_t)iq * 128 + col], gc = TC[(size_t)ic * 128 + col];
        float2 gqd = TQD[(size_t)iqd * 128 + col], gcd = TCD[(size_t)icd * 128 + col];
        float gco = TCOk[(size_t)ico * 128 + col];

        // ---- phase 1: s1,s2 = d@Wsdf (scaled); gd = d@(L2E*Wki0) ----
        f32x4 s1a = {bs1, bs1, bs1, bs1}, s1b = {0.f, 0.f, 0.f, 0.f};
        f32x4 s2a = {bs2, bs2, bs2, bs2}, s2b = {0.f, 0.f, 0.f, 0.f};
        f32x4 gda = {0.f, 0.f, 0.f, 0.f}, gdb = {0.f, 0.f, 0.f, 0.f};
        {
            bf16x8 d0 = *prd[0], d1 = *prd[1], d2 = *prd[2], d3 = *prd[3];
            s1a = MFMA16(d0, wf[0][0], s1a); s2a = MFMA16(d0, wf[1][0], s2a); gda = MFMA16(d0, wf[4][0], gda);
            s1b = MFMA16(d2, wf[0][2], s1b); s2b = MFMA16(d2, wf[1][2], s2b); gdb = MFMA16(d2, wf[4][2], gdb);
            s1a = MFMA16(d1, wf[0][1], s1a); s2a = MFMA16(d1, wf[1][1], s2a); gda = MFMA16(d1, wf[4][1], gda);
            s1b = MFMA16(d3, wf[0][3], s1b); s2b = MFMA16(d3, wf[1][3], s2b); gdb = MFMA16(d3, wf[4][3], gdb);
        }
        float s1v = (row ? s1a[1] : s1a[0]) + (row ? s1b[1] : s1b[0]);
        float s2v = (row ? s2a[1] : s2a[0]) + (row ? s2b[1] : s2b[0]);
        float gdv = (row ? gda[1] : gda[0]) + (row ? gdb[1] : gdb[0]);
        float gv = __builtin_amdgcn_rcpf(1.0f + __builtin_amdgcn_exp2f(gdv + kip0));
        float e1 = __builtin_amdgcn_exp2f(s1v), e2 = __builtin_amdgcn_exp2f(s2v);
        float sdf = (1.0f - e2) * __builtin_amdgcn_rcpf((1.0f + e1) * (1.0f + e2));
        {
            uint32_t pk = cvtpk(sdf, sdf);
            if (owner) *(unsigned short*)psw = (unsigned short)pk;
        }
        bar_lgkm();

        // ---- phase 2: p1,p2 = sdf@Wpka (scaled); own-row bias post-select ----
        f32x4 p1a = {0.f, 0.f, 0.f, 0.f}, p1b = {0.f, 0.f, 0.f, 0.f};
        f32x4 p2a = {0.f, 0.f, 0.f, 0.f}, p2b = {0.f, 0.f, 0.f, 0.f};
        {
            bf16x8 f0 = *prs[0], f1 = *prs[1], f2 = *prs[2], f3 = *prs[3];
            p1a = MFMA16(f0, wf[2][0], p1a); p2a = MFMA16(f0, wf[3][0], p2a);
            p1b = MFMA16(f2, wf[2][2], p1b); p2b = MFMA16(f2, wf[3][2], p2b);
            p1a = MFMA16(f1, wf[2][1], p1a); p2a = MFMA16(f1, wf[3][1], p2a);
            p1b = MFMA16(f3, wf[2][3], p1b); p2b = MFMA16(f3, wf[3][3], p2b);
        }
        float p1v = (row ? p1a[1] : p1a[0]) + (row ? p1b[1] : p1b[0]);
        float p2v = (row ? p2a[1] : p2a[0]) + (row ? p2b[1] : p2b[0]);
        float t1 = c0 ? tp1b : tp1a;
        float t2 = c0 ? tp2b : tp2a;
        float e1p = __builtin_amdgcn_exp2f(p1v + t1), e2p = __builtin_amdgcn_exp2f(p2v + t2);
        float pka = (1.0f - e2p) * __builtin_amdgcn_rcpf((1.0f + e1p) * (1.0f + e2p));
        h = gv * (h - pka) + pka;

        // ---- d-write for step t+1 IMMEDIATELY (critical path) ----
        {
            uint32_t pk = cvtpk(x1 - h, x1 - h);
            if (owner) *(unsigned short*)pdw = (unsigned short)pk;
        }
        // ---- y partial (off critical path): 16-lane DPP sum, masked store ----
        float yv = sum16(x1 * h);
        if (ystore) ypt[0] = yv;
        ypt += YSTR;
        bar_lgkm();

        // ---- rotate pipeline (finish gather sums here; loads waited on use) ----
        x1 = gq.x + gc.x + gqd.x + gcd.x;
        kip0 = kip1;
        kip1 = gq.y + gc.y + gqd.y + gcd.y + gco;
        c0 = c1;
        c1 = (unsigned int)ico & 1u;
    }
}

// ---------------- final: y[b][t] = sigmoid(sum of 8 wave partials); y[:,499] = 0 ------
__global__ __launch_bounds__(256) void k_yfinal(const float* __restrict__ ypart, float* __restrict__ y)
{
    int id = blockIdx.x * 256 + threadIdx.x;
    if (id >= BB * SS) return;
    int b = id / SS, t = id - b * SS;
    if (t == TT) { y[id] = 0.0f; return; }
    int rb = b >> 1, pair = b & 1;
    const float* base = ypart + (size_t)t * NRB * 16 + (size_t)rb * 16 + pair;
    float s = 0.0f;
    #pragma unroll
    for (int w = 0; w < 8; ++w) s += base[w * 2];
    y[id] = fsig(s);
}

// ---------------- launch ----------------
extern "C" void kernel_launch(void* const* d_in, const int* in_sizes, int n_in,
                              void* d_out, int out_size, void* d_ws, size_t ws_size,
                              hipStream_t stream) {
    const int* qs    = (const int*)d_in[0];
    const int* cs    = (const int*)d_in[1];
    const int* qds   = (const int*)d_in[2];
    const int* cds   = (const int*)d_in[3];
    const int* corr  = (const int*)d_in[4];
    const float* Eq    = (const float*)d_in[5];
    const float* Ec    = (const float*)d_in[6];
    const float* Eqd   = (const float*)d_in[7];
    const float* Ecd   = (const float*)d_in[8];
    const float* Ecorr = (const float*)d_in[9];
    const float* Wx    = (const float*)d_in[10];
    const float* bx    = (const float*)d_in[11];
    const float* Wsdf1 = (const float*)d_in[12];
    const float* bsdf1 = (const float*)d_in[13];
    const float* Wsdf2 = (const float*)d_in[14];
    const float* bsdf2 = (const float*)d_in[15];
    const float* Wpka1 = (const float*)d_in[16];
    const float* bpka1 = (const float*)d_in[17];
    const float* Wpka2 = (const float*)d_in[18];
    const float* bpka2 = (const float*)d_in[19];
    const float* Wki   = (const float*)d_in[20];
    const float* bki   = (const float*)d_in[21];
    const float* h0    = (const float*)d_in[22];

    char* base;
    if (ws_size >= TOTAL_WS) {
        base = (char*)d_ws;
    } else {
        void* p = nullptr;
        hipGetSymbolAddress(&p, HIP_SYMBOL(g_fb));
        base = (char*)p;
    }

    float* TQ    = (float*)(base + OFF_TQ);
    float* TC    = (float*)(base + OFF_TC);
    float* TQD   = (float*)(base + OFF_TQD);
    float* TCD   = (float*)(base + OFF_TCD);
    float* TCOk  = (float*)(base + OFF_TCOK);
    float* Tp1   = (float*)(base + OFF_TP1);
    float* Tp2   = (float*)(base + OFF_TP2);
    float* tmpA  = (float*)(base + OFF_TMPA);
    float* tmpB  = (float*)(base + OFF_TMPB);
    unsigned short* wfrag = (unsigned short*)(base + OFF_WFRAG);
    float* ypart = (float*)(base + OFF_YPART);

    k_tables<<<10906, 128, 0, stream>>>(Eq, Ec, Eqd, Ecd, Ecorr, Wx, bx,
                                        Wpka1, bpka1, Wpka2, bpka2, Wki, bki,
                                        TQ, TC, TQD, TCD, TCOk, Tp1, Tp2, tmpA, tmpB);
    k_tables2<<<10700, 128, 0, stream>>>(Wki, TQ, TC, TQD, TCD, tmpA, tmpB);
    k_wfrag<<<160, 64, 0, stream>>>(Wsdf1, Wsdf2, Wpka1, Wpka2, Wki, wfrag);
    k_rec<<<NRB, 512, 0, stream>>>(qs, cs, qds, cds, corr,
                                   (const float2*)TQ, (const float2*)TC,
                                   (const float2*)TQD, (const float2*)TCD, TCOk,
                                   wfrag, Tp1, Tp2, bsdf1, bsdf2, h0, ypart);
    k_yfinal<<<(BB * SS + 255) / 256, 256, 0, stream>>>(ypart, (float*)d_out);
}